// Round 1
// baseline (209.385 us; speedup 1.0000x reference)
//
#include <hip/hip_runtime.h>

#define BATCH   8192
#define FEAT    256
#define NCLASS  100000
#define ALPHA_C 1.0f
#define EPS_C   1e-6f

// total new_centers elements
#define NC_ELEMS (NCLASS * FEAT)          // 25,600,000
// d_out float4 vectors covering d_out[0 .. 25,600,000)
#define NVEC (NC_ELEMS / 4)               // 6,400,000

__global__ void zero_counts_kernel(int* counts) {
    int i = blockIdx.x * blockDim.x + threadIdx.x;
    if (i < NCLASS) counts[i] = 0;
}

__global__ void count_kernel(const int* __restrict__ target, int* __restrict__ counts) {
    int b = blockIdx.x * blockDim.x + threadIdx.x;
    if (b < BATCH) atomicAdd(&counts[target[b]], 1);
}

// Copy centers -> d_out shifted by +1 float. d_out is 16B aligned; the
// new_centers region d_out[1..] is 4B-misaligned for float4. Trick:
// aligned float4 load from centers, shift via __shfl_up within the wave,
// aligned float4 store to d_out. out_vec[v] = {c[4v-1], c[4v], c[4v+1], c[4v+2]}.
__global__ void copy_shift_kernel(const float* __restrict__ centers,
                                  float* __restrict__ out /* = d_out base */) {
    int v = blockIdx.x * blockDim.x + threadIdx.x;   // [0, NVEC)
    if (v >= NVEC) return;
    const float4* cvec = (const float4*)centers;
    float4 cv = cvec[v];                             // centers[4v .. 4v+3]
    int lane = threadIdx.x & 63;
    float prev = __shfl_up(cv.w, 1);                 // lane-1's c[4(v-1)+3] = c[4v-1]
    if (lane == 0) {
        prev = (v > 0) ? centers[4 * v - 1] : 0.0f;  // v==0 slot is loss, overwritten later
    }
    float4 ov;
    ov.x = prev; ov.y = cv.x; ov.z = cv.y; ov.w = cv.z;
    ((float4*)out)[v] = ov;
    // tail: d_out[NC_ELEMS] = centers[NC_ELEMS-1]
    if (v == 0) out[NC_ELEMS] = centers[NC_ELEMS - 1];
}

// One block per sample; 256 threads = FEAT.
__global__ void scatter_kernel(const float* __restrict__ features,
                               const int* __restrict__ target,
                               const float* __restrict__ centers,
                               const int* __restrict__ counts,
                               float* __restrict__ out1,      // d_out + 1
                               float* __restrict__ partials) {
    int b = blockIdx.x;
    int d = threadIdx.x;
    int t = target[b];
    float c = centers[t * FEAT + d];
    float f = features[b * FEAT + d];
    float diff = c - f;

    // loss partial: block-reduce diff^2
    float sq = diff * diff;
    #pragma unroll
    for (int off = 32; off > 0; off >>= 1) sq += __shfl_down(sq, off, 64);
    __shared__ float red[4];
    int wave = threadIdx.x >> 6;
    int lane = threadIdx.x & 63;
    if (lane == 0) red[wave] = sq;
    __syncthreads();
    if (threadIdx.x == 0) {
        partials[b] = red[0] + red[1] + red[2] + red[3];
    }

    // scatter update: new_centers -= alpha*diff/(count+eps), accumulated per class
    float inv = ALPHA_C / ((float)counts[t] + EPS_C);
    atomicAdd(&out1[t * FEAT + d], -diff * inv);
}

__global__ void finalize_kernel(const float* __restrict__ partials,
                                float* __restrict__ out0) {
    float s = 0.0f;
    for (int i = threadIdx.x; i < BATCH; i += 256) s += partials[i];
    #pragma unroll
    for (int off = 32; off > 0; off >>= 1) s += __shfl_down(s, off, 64);
    __shared__ float red[4];
    int wave = threadIdx.x >> 6;
    int lane = threadIdx.x & 63;
    if (lane == 0) red[wave] = s;
    __syncthreads();
    if (threadIdx.x == 0) {
        float total = red[0] + red[1] + red[2] + red[3];
        out0[0] = total / (float)(BATCH * FEAT);
    }
}

extern "C" void kernel_launch(void* const* d_in, const int* in_sizes, int n_in,
                              void* d_out, int out_size, void* d_ws, size_t ws_size,
                              hipStream_t stream) {
    const float* features = (const float*)d_in[0];
    const int*   target   = (const int*)d_in[1];
    const float* centers  = (const float*)d_in[2];
    float* out = (float*)d_out;

    int*   counts   = (int*)d_ws;                                   // 100000 ints
    float* partials = (float*)((char*)d_ws + NCLASS * sizeof(int)); // 8192 floats

    zero_counts_kernel<<<(NCLASS + 255) / 256, 256, 0, stream>>>(counts);
    count_kernel<<<(BATCH + 255) / 256, 256, 0, stream>>>(target, counts);
    copy_shift_kernel<<<NVEC / 256, 256, 0, stream>>>(centers, out);
    scatter_kernel<<<BATCH, FEAT, 0, stream>>>(features, target, centers, counts,
                                               out + 1, partials);
    finalize_kernel<<<1, 256, 0, stream>>>(partials, out);
}